// Round 11
// baseline (41.792 us; speedup 1.0000x reference)
//
#include <hip/hip_runtime.h>

#define SCALE_F 173.71779276130078f   // 400 / ln(10)
#define BLOCK 256
#define TPT 4                         // consecutive tokens per thread
#define PASSES 2                      // pass 0 = real, pass 1 = probe (sunk)

typedef float v2f __attribute__((ext_vector_type(2)));

__global__ void zero_ws_kernel(float* __restrict__ ws, int n) {
    int i = blockIdx.x * 256 + threadIdx.x;
    if (i < n) ws[i] = 0.0f;
}

__global__ __launch_bounds__(BLOCK, 8) void strength_main_kernel(
    const float* __restrict__ x,    // [N][6]
    const float* __restrict__ W1,   // [6][32]
    const float* __restrict__ b1,   // [32]
    const float* __restrict__ wr,   // [32]
    const float* __restrict__ brp,  // scalar
    const float* __restrict__ wz,   // [32]
    const float* __restrict__ bzp,  // scalar
    const int*   __restrict__ seg,  // [N] sorted
    int N, int nblocks,
    float* __restrict__ num,        // [G]
    float* __restrict__ den)        // [G]
{
    const int tid  = threadIdx.x;
    const int lane = tid & 63;

    const float brv = *brp;   // uniform -> s_load
    const float bzv = *bzp;

    #pragma unroll 1
    for (int pass = 0; pass < PASSES; ++pass) {
        // pass 0: own block. pass 1: rotated block (different addresses,
        // same footprint) -- defeats CSE, measures true marginal pass cost.
        int bidx = blockIdx.x + pass * (nblocks / 2);
        if (bidx >= nblocks) bidx -= nblocks;

        const int t0   = bidx * (BLOCK * TPT) + tid * TPT;
        const int kmax = (t0 >= N) ? 0 : ((N - t0 < TPT) ? (N - t0) : TPT);

        // ---- load 4 consecutive tokens (6 float4 = 96B) + 4 seg ids ----
        float a[TPT * 6];
        int   sg[TPT];
        if (kmax == TPT) {
            const float4* xp = (const float4*)(x + (size_t)t0 * 6);
            #pragma unroll
            for (int i = 0; i < 6; ++i) {
                float4 v = xp[i];
                a[4 * i + 0] = v.x; a[4 * i + 1] = v.y;
                a[4 * i + 2] = v.z; a[4 * i + 3] = v.w;
            }
            int4 s0v = *(const int4*)(seg + t0);
            sg[0] = s0v.x; sg[1] = s0v.y; sg[2] = s0v.z; sg[3] = s0v.w;
        } else {
            #pragma unroll
            for (int k = 0; k < TPT; ++k) {
                if (k < kmax) {
                    const float* xp = x + (size_t)(t0 + k) * 6;
                    #pragma unroll
                    for (int i = 0; i < 6; ++i) a[k * 6 + i] = xp[i];
                    sg[k] = seg[t0 + k];
                } else {
                    #pragma unroll
                    for (int i = 0; i < 6; ++i) a[k * 6 + i] = 0.0f;
                    sg[k] = -1;
                }
            }
        }

        // ---- token-pair packed math (v_pk_fma_f32) ----
        v2f X[2][6];
        #pragma unroll
        for (int p = 0; p < 2; ++p)
            #pragma unroll
            for (int f = 0; f < 6; ++f)
                X[p][f] = (v2f){ a[(2*p)*6 + f], a[(2*p+1)*6 + f] };

        v2f R[2], Z[2];
        R[0] = (v2f){brv, brv}; R[1] = (v2f){brv, brv};
        Z[0] = (v2f){bzv, bzv}; Z[1] = (v2f){bzv, bzv};

        #pragma unroll 2
        for (int c = 0; c < 16; ++c) {
            const float2 w0 = *(const float2*)&W1[0 * 32 + 2 * c];
            const float2 w1 = *(const float2*)&W1[1 * 32 + 2 * c];
            const float2 w2 = *(const float2*)&W1[2 * 32 + 2 * c];
            const float2 w3 = *(const float2*)&W1[3 * 32 + 2 * c];
            const float2 w4 = *(const float2*)&W1[4 * 32 + 2 * c];
            const float2 w5 = *(const float2*)&W1[5 * 32 + 2 * c];
            const float2 bb = *(const float2*)&b1[2 * c];
            const float2 rr = *(const float2*)&wr[2 * c];
            const float2 zz = *(const float2*)&wz[2 * c];

            #pragma unroll
            for (int j = 0; j < 2; ++j) {
                const float wj0 = j ? w0.y : w0.x;
                const float wj1 = j ? w1.y : w1.x;
                const float wj2 = j ? w2.y : w2.x;
                const float wj3 = j ? w3.y : w3.x;
                const float wj4 = j ? w4.y : w4.x;
                const float wj5 = j ? w5.y : w5.x;
                const float bbj = j ? bb.y : bb.x;
                const float rrj = j ? rr.y : rr.x;
                const float zzj = j ? zz.y : zz.x;
                const v2f vw0 = (v2f){wj0, wj0}, vw1 = (v2f){wj1, wj1};
                const v2f vw2 = (v2f){wj2, wj2}, vw3 = (v2f){wj3, wj3};
                const v2f vw4 = (v2f){wj4, wj4}, vw5 = (v2f){wj5, wj5};
                const v2f vbb = (v2f){bbj, bbj};
                const v2f vrr = (v2f){rrj, rrj}, vzz = (v2f){zzj, zzj};
                #pragma unroll
                for (int p = 0; p < 2; ++p) {
                    v2f h = X[p][0]*vw0 + (X[p][1]*vw1 + (X[p][2]*vw2 +
                            (X[p][3]*vw3 + (X[p][4]*vw4 + (X[p][5]*vw5 + vbb)))));
                    h = __builtin_elementwise_max(h, (v2f){0.f, 0.f});
                    R[p] = h * vrr + R[p];
                    Z[p] = h * vzz + Z[p];
                }
            }
        }

        float rv[TPT] = { R[0].x, R[0].y, R[1].x, R[1].y };
        float zv[TPT] = { Z[0].x, Z[0].y, Z[1].x, Z[1].y };

        // ---- run accumulation + wave scan (both passes; atomics pass 0 only) ----
        int   key = (kmax > 0) ? sg[0] : -1;
        float E = 0.0f, ER = 0.0f;
        #pragma unroll
        for (int k = 0; k < TPT; ++k) {
            if (k < kmax) {
                float e = __expf(zv[k]);       // no max-shift: ratio invariant
                if (sg[k] != key) {
                    if (pass == 0) {
                        atomicAdd(&den[key], E);
                        atomicAdd(&num[key], ER);
                    } else {
                        asm volatile("" :: "v"(E), "v"(ER));   // keep alive
                    }
                    key = sg[k]; E = 0.0f; ER = 0.0f;
                }
                E += e; ER = fmaf(e, rv[k], ER);
            }
        }

        #pragma unroll
        for (int d = 1; d < 64; d <<= 1) {
            int   k2 = __shfl_up(key, d);
            float E2 = __shfl_up(E,   d);
            float R2 = __shfl_up(ER,  d);
            if (lane >= d && k2 == key) { E += E2; ER += R2; }
        }
        int knext = __shfl_down(key, 1);
        bool last = (lane == 63) || (knext != key);
        if (pass == 0) {
            if (last && key >= 0) {
                atomicAdd(&den[key], E);
                atomicAdd(&num[key], ER);
            }
        } else {
            asm volatile("" :: "v"(E), "v"(ER), "v"((float)(last ? 1.f : 0.f)));
        }
    }
}

__global__ void finalize_kernel(const float* __restrict__ num,
                                const float* __restrict__ den,
                                float* __restrict__ out, int G) {
    int g = blockIdx.x * 256 + threadIdx.x;
    if (g < G) {
        float d = den[g];
        out[g] = (d > 0.0f) ? (SCALE_F * num[g] / d) : 0.0f;
    }
}

extern "C" void kernel_launch(void* const* d_in, const int* in_sizes, int n_in,
                              void* d_out, int out_size, void* d_ws, size_t ws_size,
                              hipStream_t stream) {
    const float* x   = (const float*)d_in[0];
    const float* W1  = (const float*)d_in[1];
    const float* b1  = (const float*)d_in[2];
    const float* wr  = (const float*)d_in[3];
    const float* br  = (const float*)d_in[4];
    const float* wz  = (const float*)d_in[5];
    const float* bz  = (const float*)d_in[6];
    const int*   seg = (const int*)d_in[7];

    int N = in_sizes[7];     // 2097152
    int G = out_size;        // 8192

    float* num = (float*)d_ws;
    float* den = num + G;
    float* out = (float*)d_out;

    int zn = 2 * G;
    zero_ws_kernel<<<(zn + 255) / 256, 256, 0, stream>>>(num, zn);

    long tokens_per_block = (long)BLOCK * TPT;   // 1024
    int  nblocks = (int)(((long)N + tokens_per_block - 1) / tokens_per_block);
    strength_main_kernel<<<nblocks, BLOCK, 0, stream>>>(
        x, W1, b1, wr, br, wz, bz, seg, N, nblocks, num, den);

    finalize_kernel<<<(G + 255) / 256, 256, 0, stream>>>(num, den, out, G);
}

// Round 12
// 31.409 us; speedup vs baseline: 1.3306x; 1.3306x over previous
//
#include <hip/hip_runtime.h>

#define SCALE_F 173.71779276130078f   // 400 / ln(10)
#define BLOCK 256
#define TPT 4                         // consecutive tokens per thread

typedef float v2f __attribute__((ext_vector_type(2)));

// VOP3P v_pk_fma_f32 with op_sel broadcast of the SGPR-pair weight operand.
// srcB = SGPR pair {w.x, w.y}:  *_LO broadcasts w.x to both halves,
// *_HI broadcasts w.y.  srcA/srcC are normal packed VGPR pairs.
// op_sel[i]   = half feeding the LO result (0=lo,1=hi)
// op_sel_hi[i]= half feeding the HI result
#define PKFMA_CLO(d,a,b,c) asm("v_pk_fma_f32 %0, %1, %2, %3 op_sel:[0,0,0] op_sel_hi:[1,0,1]" : "=v"(d) : "v"(a), "s"(b), "v"(c))
#define PKFMA_CHI(d,a,b,c) asm("v_pk_fma_f32 %0, %1, %2, %3 op_sel:[0,1,0] op_sel_hi:[1,1,1]" : "=v"(d) : "v"(a), "s"(b), "v"(c))
// bias start: srcC is a VGPR pair {bb.x,bb.y}, broadcast lo/hi like srcB
#define PKFMA_BLO(d,a,b,c) asm("v_pk_fma_f32 %0, %1, %2, %3 op_sel:[0,0,0] op_sel_hi:[1,0,0]" : "=v"(d) : "v"(a), "s"(b), "v"(c))
#define PKFMA_BHI(d,a,b,c) asm("v_pk_fma_f32 %0, %1, %2, %3 op_sel:[0,1,1] op_sel_hi:[1,1,1]" : "=v"(d) : "v"(a), "s"(b), "v"(c))
// accumulate d += a * broadcast(b)
#define PKACC_LO(d,a,b)  asm("v_pk_fma_f32 %0, %1, %2, %0 op_sel:[0,0,0] op_sel_hi:[1,0,1]" : "+v"(d) : "v"(a), "s"(b))
#define PKACC_HI(d,a,b)  asm("v_pk_fma_f32 %0, %1, %2, %0 op_sel:[0,1,0] op_sel_hi:[1,1,1]" : "+v"(d) : "v"(a), "s"(b))

__global__ void zero_ws_kernel(float* __restrict__ ws, int n) {
    int i = blockIdx.x * 256 + threadIdx.x;
    if (i < n) ws[i] = 0.0f;
}

__global__ __launch_bounds__(BLOCK, 8) void strength_main_kernel(
    const float* __restrict__ x,    // [N][6]
    const float* __restrict__ W1,   // [6][32]
    const float* __restrict__ b1,   // [32]
    const float* __restrict__ wr,   // [32]
    const float* __restrict__ brp,  // scalar
    const float* __restrict__ wz,   // [32]
    const float* __restrict__ bzp,  // scalar
    const int*   __restrict__ seg,  // [N] sorted
    int N,
    float* __restrict__ num,        // [G]
    float* __restrict__ den)        // [G]
{
    const int tid  = threadIdx.x;
    const int lane = tid & 63;

    const int t0   = blockIdx.x * (BLOCK * TPT) + tid * TPT;
    const int kmax = (t0 >= N) ? 0 : ((N - t0 < TPT) ? (N - t0) : TPT);

    // ---- load 4 consecutive tokens (6 float4 = 96B) + 4 seg ids ----
    float a[TPT * 6];
    int   sg[TPT];
    if (kmax == TPT) {
        const float4* xp = (const float4*)(x + (size_t)t0 * 6);
        #pragma unroll
        for (int i = 0; i < 6; ++i) {
            float4 v = xp[i];
            a[4 * i + 0] = v.x; a[4 * i + 1] = v.y;
            a[4 * i + 2] = v.z; a[4 * i + 3] = v.w;
        }
        int4 s0v = *(const int4*)(seg + t0);
        sg[0] = s0v.x; sg[1] = s0v.y; sg[2] = s0v.z; sg[3] = s0v.w;
    } else {
        #pragma unroll
        for (int k = 0; k < TPT; ++k) {
            if (k < kmax) {
                const float* xp = x + (size_t)(t0 + k) * 6;
                #pragma unroll
                for (int i = 0; i < 6; ++i) a[k * 6 + i] = xp[i];
                sg[k] = seg[t0 + k];
            } else {
                #pragma unroll
                for (int i = 0; i < 6; ++i) a[k * 6 + i] = 0.0f;
                sg[k] = -1;
            }
        }
    }

    // ---- token-pair packed layout: X[p][f] = {tok(2p).f, tok(2p+1).f} ----
    v2f X[2][6];
    #pragma unroll
    for (int p = 0; p < 2; ++p)
        #pragma unroll
        for (int f = 0; f < 6; ++f)
            X[p][f] = (v2f){ a[(2*p)*6 + f], a[(2*p+1)*6 + f] };

    const float brv = *brp;   // uniform -> s_load
    const float bzv = *bzp;

    v2f R[2], Z[2];
    R[0] = (v2f){brv, brv}; R[1] = (v2f){brv, brv};
    Z[0] = (v2f){bzv, bzv}; Z[1] = (v2f){bzv, bzv};

    // ---- MLP: 16 col-pairs; weights stay in SGPR pairs, broadcast via
    //      op_sel (no splat movs).  9 pk-ops per (p,j). ----
    #pragma unroll 2
    for (int c = 0; c < 16; ++c) {
        const double w0 = *(const double*)&W1[0 * 32 + 2 * c];
        const double w1 = *(const double*)&W1[1 * 32 + 2 * c];
        const double w2 = *(const double*)&W1[2 * 32 + 2 * c];
        const double w3 = *(const double*)&W1[3 * 32 + 2 * c];
        const double w4 = *(const double*)&W1[4 * 32 + 2 * c];
        const double w5 = *(const double*)&W1[5 * 32 + 2 * c];
        const double rr = *(const double*)&wr[2 * c];
        const double zz = *(const double*)&wz[2 * c];
        // bias pair -> VGPR pair once per c (srcC can't be a 2nd SGPR operand)
        const float2 bbf = *(const float2*)&b1[2 * c];
        v2f vbb = (v2f){ bbf.x, bbf.y };

        #pragma unroll
        for (int p = 0; p < 2; ++p) {
            v2f h;
            // column 2c  (broadcast .x of each weight pair)
            PKFMA_BLO(h, X[p][5], w5, vbb);
            PKFMA_CLO(h, X[p][4], w4, h);
            PKFMA_CLO(h, X[p][3], w3, h);
            PKFMA_CLO(h, X[p][2], w2, h);
            PKFMA_CLO(h, X[p][1], w1, h);
            PKFMA_CLO(h, X[p][0], w0, h);
            h = __builtin_elementwise_max(h, (v2f){0.f, 0.f});   // v_pk_max_f32
            PKACC_LO(R[p], h, rr);
            PKACC_LO(Z[p], h, zz);
            // column 2c+1 (broadcast .y)
            PKFMA_BHI(h, X[p][5], w5, vbb);
            PKFMA_CHI(h, X[p][4], w4, h);
            PKFMA_CHI(h, X[p][3], w3, h);
            PKFMA_CHI(h, X[p][2], w2, h);
            PKFMA_CHI(h, X[p][1], w1, h);
            PKFMA_CHI(h, X[p][0], w0, h);
            h = __builtin_elementwise_max(h, (v2f){0.f, 0.f});
            PKACC_HI(R[p], h, rr);
            PKACC_HI(Z[p], h, zz);
        }
    }

    float rv[TPT] = { R[0].x, R[0].y, R[1].x, R[1].y };
    float zv[TPT] = { Z[0].x, Z[0].y, Z[1].x, Z[1].y };

    // ---- per-thread run accumulation; interior boundary flushes to global ----
    int   key = (kmax > 0) ? sg[0] : -1;
    float E = 0.0f, ER = 0.0f;
    #pragma unroll
    for (int k = 0; k < TPT; ++k) {
        if (k < kmax) {
            float e = __expf(zv[k]);       // no max-shift: ratio invariant
            if (sg[k] != key) {            // rare (~1.5% of threads)
                atomicAdd(&den[key], E);
                atomicAdd(&num[key], ER);
                key = sg[k]; E = 0.0f; ER = 0.0f;
            }
            E += e; ER = fmaf(e, rv[k], ER);
        }
    }

    // ---- one segmented inclusive scan per wave over lane tails ----
    #pragma unroll
    for (int d = 1; d < 64; d <<= 1) {
        int   k2 = __shfl_up(key, d);
        float E2 = __shfl_up(E,   d);
        float R2 = __shfl_up(ER,  d);
        if (lane >= d && k2 == key) { E += E2; ER += R2; }
    }
    int knext = __shfl_down(key, 1);
    bool last = (lane == 63) || (knext != key);
    if (last && key >= 0) {
        atomicAdd(&den[key], E);
        atomicAdd(&num[key], ER);
    }
}

__global__ void finalize_kernel(const float* __restrict__ num,
                                const float* __restrict__ den,
                                float* __restrict__ out, int G) {
    int g = blockIdx.x * 256 + threadIdx.x;
    if (g < G) {
        float d = den[g];
        out[g] = (d > 0.0f) ? (SCALE_F * num[g] / d) : 0.0f;
    }
}

extern "C" void kernel_launch(void* const* d_in, const int* in_sizes, int n_in,
                              void* d_out, int out_size, void* d_ws, size_t ws_size,
                              hipStream_t stream) {
    const float* x   = (const float*)d_in[0];
    const float* W1  = (const float*)d_in[1];
    const float* b1  = (const float*)d_in[2];
    const float* wr  = (const float*)d_in[3];
    const float* br  = (const float*)d_in[4];
    const float* wz  = (const float*)d_in[5];
    const float* bz  = (const float*)d_in[6];
    const int*   seg = (const int*)d_in[7];

    int N = in_sizes[7];     // 2097152
    int G = out_size;        // 8192

    float* num = (float*)d_ws;
    float* den = num + G;
    float* out = (float*)d_out;

    int zn = 2 * G;
    zero_ws_kernel<<<(zn + 255) / 256, 256, 0, stream>>>(num, zn);

    long tokens_per_block = (long)BLOCK * TPT;   // 1024
    int  nblocks = (int)(((long)N + tokens_per_block - 1) / tokens_per_block);
    strength_main_kernel<<<nblocks, BLOCK, 0, stream>>>(
        x, W1, b1, wr, br, wz, bz, seg, N, num, den);

    finalize_kernel<<<(G + 255) / 256, 256, 0, stream>>>(num, den, out, G);
}